// Round 9
// baseline (411.777 us; speedup 1.0000x reference)
//
#include <hip/hip_runtime.h>
#include <math.h>

#define B_ 8
#define N_ 16384
#define G_ 128      // NUM_GROUPS
#define GS_ 32      // GROUP_SIZE
#define UK_ 128     // UPSCALE_K
#define FPS_T 1024
#define FPS_W 16    // waves per FPS block
#define FPS_BLK 4   // blocks (CUs) per batch
#define SLICE (N_ / FPS_BLK)     // 4096 points per block
#define PPT (SLICE / FPS_T)      // 4 points per thread
#define BQ_T 512
#define BQ_W 8      // waves per group block

// Exact-rounding distance^2, matching numpy: ((dx*dx + dy*dy) + dz*dz), no FMA.
__device__ __forceinline__ float dist2(float x, float y, float z,
                                       float cx, float cy, float cz) {
    float dx = __fsub_rn(x, cx);
    float dy = __fsub_rn(y, cy);
    float dz = __fsub_rn(z, cz);
    return __fadd_rn(__fadd_rn(__fmul_rn(dx, dx), __fmul_rn(dy, dy)),
                     __fmul_rn(dz, dz));
}

__device__ __forceinline__ unsigned long long shfl_xor_u64(unsigned long long v, int m) {
    int lo = __shfl_xor((int)(unsigned)(v & 0xffffffffull), m);
    int hi = __shfl_xor((int)(unsigned)(v >> 32), m);
    return ((unsigned long long)(unsigned)hi << 32) | (unsigned)lo;
}

__device__ __forceinline__ unsigned long long umax64(unsigned long long a,
                                                     unsigned long long b) {
    return a > b ? a : b;
}

// Wave64 max-reduce on the VALU pipe via DPP (no DS traffic).
__device__ __forceinline__ unsigned wave_umax_bcast(unsigned v) {
    unsigned t;
    t = (unsigned)__builtin_amdgcn_update_dpp(0, (int)v, 0x111, 0xf, 0xf, false); v = v > t ? v : t;
    t = (unsigned)__builtin_amdgcn_update_dpp(0, (int)v, 0x112, 0xf, 0xf, false); v = v > t ? v : t;
    t = (unsigned)__builtin_amdgcn_update_dpp(0, (int)v, 0x114, 0xf, 0xf, false); v = v > t ? v : t;
    t = (unsigned)__builtin_amdgcn_update_dpp(0, (int)v, 0x118, 0xf, 0xf, false); v = v > t ? v : t;
    t = (unsigned)__builtin_amdgcn_update_dpp(0, (int)v, 0x142, 0xa, 0xf, false); v = v > t ? v : t;
    t = (unsigned)__builtin_amdgcn_update_dpp(0, (int)v, 0x143, 0xc, 0xf, false); v = v > t ? v : t;
    return (unsigned)__builtin_amdgcn_readlane((int)v, 63);
}
__device__ __forceinline__ unsigned wave_umin_bcast(unsigned v) {
    unsigned t;
    t = (unsigned)__builtin_amdgcn_update_dpp(-1, (int)v, 0x111, 0xf, 0xf, false); v = v < t ? v : t;
    t = (unsigned)__builtin_amdgcn_update_dpp(-1, (int)v, 0x112, 0xf, 0xf, false); v = v < t ? v : t;
    t = (unsigned)__builtin_amdgcn_update_dpp(-1, (int)v, 0x114, 0xf, 0xf, false); v = v < t ? v : t;
    t = (unsigned)__builtin_amdgcn_update_dpp(-1, (int)v, 0x118, 0xf, 0xf, false); v = v < t ? v : t;
    t = (unsigned)__builtin_amdgcn_update_dpp(-1, (int)v, 0x142, 0xa, 0xf, false); v = v < t ? v : t;
    t = (unsigned)__builtin_amdgcn_update_dpp(-1, (int)v, 0x143, 0xc, 0xf, false); v = v < t ? v : t;
    return (unsigned)__builtin_amdgcn_readlane((int)v, 63);
}

// ---------------------------------------------------------------------------
// Kernel 0: zero the cross-block slots + gl (ws is poisoned 0xAA; must be
// stream-ordered BEFORE fps so no block can see poison as a valid key).
// ---------------------------------------------------------------------------
__global__ void init_kernel(unsigned long long* __restrict__ slots,
                            int* __restrict__ gl) {
    int t = threadIdx.x;                 // 1024 threads
#pragma unroll
    for (int i = 0; i < (B_ * G_ * FPS_BLK) / 1024; i++)
        slots[i * 1024 + t] = 0ull;
    if (t < B_) gl[t] = 0;
}

// ---------------------------------------------------------------------------
// Kernel 1: FPS, 4 blocks per batch (one slice of 4096 points each), plus
// fused CNMS in the slice-0 block.
//
// r8 post-mortem: single-block FPS was ~70% VALU-issue-bound on its 1 CU
// (~3200 of 4590 cyc/step). Fix = use 4 CUs per batch: local VALU drops 4x;
// per-step cross-block argmax via device-scope atomics (u64 monotone key,
// sentinel 0 is unreachable by any real key), bit-identical reduction.
// Block->XCD heuristic: blockIdx = slice*8 + b keeps a batch's blocks on
// one XCD (%8 round-robin) for L2-local sync; AGENT-scope release/acquire
// makes it correct regardless of placement.
// ---------------------------------------------------------------------------
__global__ __launch_bounds__(FPS_T, 4) void fps_cnms_kernel(
    const float4* __restrict__ pts, const int* __restrict__ lengths,
    float* __restrict__ centers_out, int* __restrict__ keep_out,
    unsigned long long* __restrict__ slots) {
    const int b = blockIdx.x & 7;        // batch
    const int slice = blockIdx.x >> 3;   // 0..3
    const int t = threadIdx.x;
    const int lane = t & 63;
    const int wv = t >> 6;
    const int len = lengths[b];
    const float4* p = pts + (size_t)b * N_;
    const int base = slice * SLICE;

    __shared__ float4 s_xy4[SLICE / 2];                   // 32 KB: (xA,yA,xB,yB)
    __shared__ __align__(16) unsigned long long s_part[FPS_W];
    __shared__ int s_bcn[2];
    __shared__ float s_cen[G_][3];                        // centers for CNMS (slice 0)

    // Stage xy pairs -> LDS; z + running min-dist in registers.
    float zs[PPT], mind[PPT];
#pragma unroll
    for (int i2 = 0; i2 < PPT / 2; i2++) {
        int nA = base + (2 * i2) * FPS_T + t;
        int nB = base + (2 * i2 + 1) * FPS_T + t;
        float4 qA = p[nA];
        float4 qB = p[nB];
        s_xy4[i2 * FPS_T + t] = make_float4(qA.x, qA.y, qB.x, qB.y);
        zs[2 * i2]     = qA.z;
        zs[2 * i2 + 1] = qB.z;
        mind[2 * i2]     = (nA < len) ? INFINITY : -INFINITY;
        mind[2 * i2 + 1] = (nB < len) ? INFINITY : -INFINITY;
    }
    __syncthreads();

    int n = 0;   // winner index (uniform across ALL blocks of batch b)
    for (int k = 0; k < G_; k++) {
        float4 c = p[n];   // wave-uniform broadcast load
        float cx = c.x, cy = c.y, cz = c.z;
        if (slice == 0 && t == 0) {
            centers_out[(b * G_ + k) * 3 + 0] = cx;
            centers_out[(b * G_ + k) * 3 + 1] = cy;
            centers_out[(b * G_ + k) * 3 + 2] = cz;
            s_cen[k][0] = cx; s_cen[k][1] = cy; s_cen[k][2] = cz;
        }
        if (k == G_ - 1) break;   // last argmax is discarded by the reference

        // Local update + argmax (ascending n order => strict > keeps smallest n).
        float bv = -INFINITY;
        int bn = 0x7fffffff;
#pragma unroll
        for (int i2 = 0; i2 < PPT / 2; i2++) {
            float4 xy = s_xy4[i2 * FPS_T + t];            // ds_read_b128, 2 points
            float dA = dist2(xy.x, xy.y, zs[2 * i2],     cx, cy, cz);
            float dB = dist2(xy.z, xy.w, zs[2 * i2 + 1], cx, cy, cz);
            float mA = fminf(mind[2 * i2], dA);
            float mB = fminf(mind[2 * i2 + 1], dB);
            mind[2 * i2] = mA;
            mind[2 * i2 + 1] = mB;
            if (mA > bv) { bv = mA; bn = base + (2 * i2) * FPS_T + t; }
            if (mB > bv) { bv = mB; bn = base + (2 * i2 + 1) * FPS_T + t; }
        }
        // Monotone u32 key of bv (any non-NaN float -> nonzero hi word).
        unsigned u = __float_as_uint(bv);
        u = (u & 0x80000000u) ? ~u : (u | 0x80000000u);

        // Wave argmax (VALU pipe): max value, then min index among ties.
        unsigned wmax = wave_umax_bcast(u);
        unsigned ik = (u == wmax) ? (unsigned)bn : 0xffffffffu;
        unsigned wbn = wave_umin_bcast(ik);

        if (lane == 0)
            s_part[wv] = ((unsigned long long)wmax << 32) | (unsigned)(~wbn);
        __syncthreads();

        // Wave 0 reduces the 16 wave partials; t0 does the cross-block merge.
        if (wv == 0) {
            unsigned long long kk = s_part[lane & 15];
#pragma unroll
            for (int off = 8; off; off >>= 1)
                kk = umax64(kk, shfl_xor_u64(kk, off));
            if (lane == 0) {
                unsigned long long* slot = slots + ((size_t)b * G_ + k) * FPS_BLK;
                __hip_atomic_store(&slot[slice], kk, __ATOMIC_RELEASE,
                                   __HIP_MEMORY_SCOPE_AGENT);
                unsigned long long best = kk;
#pragma unroll
                for (int j = 0; j < FPS_BLK; j++) {
                    if (j == slice) continue;
                    unsigned long long v;
                    while ((v = __hip_atomic_load(&slot[j], __ATOMIC_ACQUIRE,
                                                  __HIP_MEMORY_SCOPE_AGENT)) == 0ull)
                        __builtin_amdgcn_s_sleep(1);
                    best = umax64(best, v);
                }
                s_bcn[k & 1] = (int)(~(unsigned)(best & 0xffffffffull));
            }
        }
        __syncthreads();
        n = s_bcn[k & 1];                                 // broadcast ds_read_b32
    }

    // ---- fused CNMS on wave 0 of the slice-0 block ----
    if (slice == 0 && t < 64) {
        const float THR = (float)((2.0 * 0.1 * (1.0 - 0.7)) * (2.0 * 0.1 * (1.0 - 0.7)));
        float ax = s_cen[t][0],      ay = s_cen[t][1],      az = s_cen[t][2];
        float ex = s_cen[t + 64][0], ey = s_cen[t + 64][1], ez = s_cen[t + 64][2];
        bool k0 = false, k1 = false;
        for (int j = 0; j < G_; j++) {
            float jx = s_cen[j][0], jy = s_cen[j][1], jz = s_cen[j][2];
            bool c0 = k0 && (dist2(ax, ay, az, jx, jy, jz) < THR);
            bool c1 = k1 && (dist2(ex, ey, ez, jx, jy, jz) < THR);
            bool conflict = __any(c0 || c1);
            if (j == t)      k0 = !conflict;
            if (j == t + 64) k1 = !conflict;
        }
        keep_out[b * G_ + t]      = k0 ? 1 : 0;
        keep_out[b * G_ + t + 64] = k1 ? 1 : 0;
    }
}

// ---------------------------------------------------------------------------
// Kernel 2: per-(b,g) ball query (first 128 by index) + top-32 by energy +
// gather/normalize. One 512-thread block per group.
// ---------------------------------------------------------------------------
__global__ __launch_bounds__(BQ_T) void group_kernel(
    const float4* __restrict__ pts, const int* __restrict__ lengths,
    const float* __restrict__ centers, const int* __restrict__ keep,
    float* __restrict__ groups_out, int* __restrict__ gl) {
    const int bid = blockIdx.x;          // b*128 + g
    const int b = bid >> 7;
    const int t = threadIdx.x;
    const int lane = t & 63;
    const int wv = t >> 6;

    const float cx = centers[bid * 3 + 0];
    const float cy = centers[bid * 3 + 1];
    const float cz = centers[bid * 3 + 2];
    float4* out4 = (float4*)(groups_out + (size_t)bid * GS_ * 4);

    if (!keep[bid]) {
        if (t < GS_) {
            float4 o;
            o.x = __fdiv_rn(__fsub_rn(0.f, cx), 0.1f);
            o.y = __fdiv_rn(__fsub_rn(0.f, cy), 0.1f);
            o.z = __fdiv_rn(__fsub_rn(0.f, cz), 0.1f);
            o.w = 0.f;
            out4[t] = o;
        }
        return;
    }

    __shared__ int   s_widx[BQ_W][UK_];
    __shared__ float s_wen[BQ_W][UK_];
    __shared__ int   s_wcnt[BQ_W];
    __shared__ int   s_list[UK_];
    __shared__ float s_en[UK_];
    __shared__ int   s_ord[GS_];

    const int len = lengths[b];
    const float R2 = (float)(0.1 * 0.1);
    const float4* p = pts + (size_t)b * N_;

    // Per-wave ordered stream compaction over its contiguous eighth.
    {
        const int base0 = wv * (N_ / BQ_W);
        int cnt = 0;
        for (int it = 0; it < (N_ / BQ_W) / 64; it++) {
            int n = base0 + it * 64 + lane;
            float4 q = p[n];
            float d2 = dist2(q.x, q.y, q.z, cx, cy, cz);
            bool pred = (n < len) && (d2 <= R2);
            unsigned long long m = __ballot(pred);
            int prefix = __popcll(m & ((1ull << lane) - 1ull));
            int slot = cnt + prefix;
            if (pred && slot < UK_) { s_widx[wv][slot] = n; s_wen[wv][slot] = q.w; }
            cnt += __popcll(m);
        }
        if (lane == 0) s_wcnt[wv] = (cnt < UK_) ? cnt : UK_;
    }
    __syncthreads();

    int M = 0;
#pragma unroll
    for (int w = 0; w < BQ_W; w++) M += s_wcnt[w];
    if (M > UK_) M = UK_;

    // Ordered merge into unified first-M list.
    if (t < UK_ && t < M) {
        int j = t, w = 0;
        while (w < BQ_W - 1 && j >= s_wcnt[w]) { j -= s_wcnt[w]; w++; }
        s_list[t] = s_widx[w][j];
        s_en[t]   = s_wen[w][j];
    }
    __syncthreads();

    // top-32 by energy, tie -> smaller list position (matches lax.top_k)
    if (wv == 0) {
        float v0 = (lane < M) ? s_en[lane] : -INFINITY;
        float v1 = (lane + 64 < M) ? s_en[lane + 64] : -INFINITY;
        for (int k = 0; k < GS_; k++) {
            float bv; int bs;
            if (v0 >= v1) { bv = v0; bs = lane; }
            else          { bv = v1; bs = lane + 64; }
#pragma unroll
            for (int off = 32; off; off >>= 1) {
                float ov = __shfl_xor(bv, off);
                int   os = __shfl_xor(bs, off);
                bool tk = (ov > bv) || (ov == bv && os < bs);
                bv = tk ? ov : bv; bs = tk ? os : bs;
            }
            if (lane == 0) s_ord[k] = (bv == -INFINITY) ? -1 : bs;
            if (bs == lane)           v0 = -INFINITY;
            else if (bs == lane + 64) v1 = -INFINITY;
        }
    }
    __syncthreads();

    if (t < GS_) {
        int o0 = s_ord[0];
        int first = (o0 >= 0) ? s_list[o0] : -1;
        int ok = s_ord[t];
        int ti = (ok >= 0) ? s_list[ok] : -1;
        int f = (ti == -1) ? first : ti;
        float px = 0.f, py = 0.f, pz = 0.f, pw = 0.f;
        if (f >= 0) { float4 q = p[f]; px = q.x; py = q.y; pz = q.z; pw = q.w; }
        float4 o;
        o.x = __fdiv_rn(__fsub_rn(px, cx), 0.1f);
        o.y = __fdiv_rn(__fsub_rn(py, cy), 0.1f);
        o.z = __fdiv_rn(__fsub_rn(pz, cz), 0.1f);
        o.w = __fdiv_rn(pw, 0.1f);
        out4[t] = o;
    }
    if (t == 0 && M >= GS_) atomicAdd(&gl[b], 1);
}

// ---------------------------------------------------------------------------
// Kernel 3: embedding mask
// ---------------------------------------------------------------------------
__global__ void mask_kernel(const int* __restrict__ gl, float* __restrict__ mask_out) {
    int t = threadIdx.x;                 // 1024 threads
    int b = t >> 7, g = t & 127;
    mask_out[t] = (g < gl[b]) ? 1.0f : 0.0f;
}

extern "C" void kernel_launch(void* const* d_in, const int* in_sizes, int n_in,
                              void* d_out, int out_size, void* d_ws, size_t ws_size,
                              hipStream_t stream) {
    const float4* pts = (const float4*)d_in[0];
    const int* lengths = (const int*)d_in[1];
    float* out = (float*)d_out;
    float* groups = out;                               // B*G*GS*4 = 131072
    float* centers = out + (size_t)B_ * G_ * GS_ * 4;  // +3072
    float* mask = centers + (size_t)B_ * G_ * 3;       // +1024
    unsigned long long* slots = (unsigned long long*)d_ws;  // B*G*FPS_BLK u64
    int* keep = (int*)(slots + B_ * G_ * FPS_BLK);     // B*G ints
    int* gl = keep + B_ * G_;                          // B ints

    hipLaunchKernelGGL(init_kernel, dim3(1), dim3(1024), 0, stream, slots, gl);
    hipLaunchKernelGGL(fps_cnms_kernel, dim3(B_ * FPS_BLK), dim3(FPS_T), 0, stream,
                       pts, lengths, centers, keep, slots);
    hipLaunchKernelGGL(group_kernel, dim3(B_ * G_), dim3(BQ_T), 0, stream,
                       pts, lengths, centers, keep, groups, gl);
    hipLaunchKernelGGL(mask_kernel, dim3(1), dim3(B_ * G_), 0, stream, gl, mask);
}

// Round 10
// 318.446 us; speedup vs baseline: 1.2931x; 1.2931x over previous
//
#include <hip/hip_runtime.h>
#include <math.h>

#define B_ 8
#define N_ 16384
#define G_ 128      // NUM_GROUPS
#define GS_ 32      // GROUP_SIZE
#define UK_ 128     // UPSCALE_K
#define FPS_T 1024
#define FPS_W 16    // waves per FPS block
#define FPS_BLK 4   // blocks (CUs) per batch
#define SLICE (N_ / FPS_BLK)     // 4096 points per block
#define PPT (SLICE / FPS_T)      // 4 points per thread
#define BQ_T 512
#define BQ_W 8      // waves per group block

// Exact-rounding distance^2, matching numpy: ((dx*dx + dy*dy) + dz*dz), no FMA.
__device__ __forceinline__ float dist2(float x, float y, float z,
                                       float cx, float cy, float cz) {
    float dx = __fsub_rn(x, cx);
    float dy = __fsub_rn(y, cy);
    float dz = __fsub_rn(z, cz);
    return __fadd_rn(__fadd_rn(__fmul_rn(dx, dx), __fmul_rn(dy, dy)),
                     __fmul_rn(dz, dz));
}

__device__ __forceinline__ unsigned long long shfl_xor_u64(unsigned long long v, int m) {
    int lo = __shfl_xor((int)(unsigned)(v & 0xffffffffull), m);
    int hi = __shfl_xor((int)(unsigned)(v >> 32), m);
    return ((unsigned long long)(unsigned)hi << 32) | (unsigned)lo;
}

__device__ __forceinline__ unsigned long long umax64(unsigned long long a,
                                                     unsigned long long b) {
    return a > b ? a : b;
}

// Wave64 max-reduce on the VALU pipe via DPP (no DS traffic).
__device__ __forceinline__ unsigned wave_umax_bcast(unsigned v) {
    unsigned t;
    t = (unsigned)__builtin_amdgcn_update_dpp(0, (int)v, 0x111, 0xf, 0xf, false); v = v > t ? v : t;
    t = (unsigned)__builtin_amdgcn_update_dpp(0, (int)v, 0x112, 0xf, 0xf, false); v = v > t ? v : t;
    t = (unsigned)__builtin_amdgcn_update_dpp(0, (int)v, 0x114, 0xf, 0xf, false); v = v > t ? v : t;
    t = (unsigned)__builtin_amdgcn_update_dpp(0, (int)v, 0x118, 0xf, 0xf, false); v = v > t ? v : t;
    t = (unsigned)__builtin_amdgcn_update_dpp(0, (int)v, 0x142, 0xa, 0xf, false); v = v > t ? v : t;
    t = (unsigned)__builtin_amdgcn_update_dpp(0, (int)v, 0x143, 0xc, 0xf, false); v = v > t ? v : t;
    return (unsigned)__builtin_amdgcn_readlane((int)v, 63);
}
__device__ __forceinline__ unsigned wave_umin_bcast(unsigned v) {
    unsigned t;
    t = (unsigned)__builtin_amdgcn_update_dpp(-1, (int)v, 0x111, 0xf, 0xf, false); v = v < t ? v : t;
    t = (unsigned)__builtin_amdgcn_update_dpp(-1, (int)v, 0x112, 0xf, 0xf, false); v = v < t ? v : t;
    t = (unsigned)__builtin_amdgcn_update_dpp(-1, (int)v, 0x114, 0xf, 0xf, false); v = v < t ? v : t;
    t = (unsigned)__builtin_amdgcn_update_dpp(-1, (int)v, 0x118, 0xf, 0xf, false); v = v < t ? v : t;
    t = (unsigned)__builtin_amdgcn_update_dpp(-1, (int)v, 0x142, 0xa, 0xf, false); v = v < t ? v : t;
    t = (unsigned)__builtin_amdgcn_update_dpp(-1, (int)v, 0x143, 0xc, 0xf, false); v = v < t ? v : t;
    return (unsigned)__builtin_amdgcn_readlane((int)v, 63);
}

// ---------------------------------------------------------------------------
// Kernel 0: zero the cross-block slots + gl (ws is poisoned 0xAA; must be
// stream-ordered BEFORE fps so no block can see poison as a valid key).
// ---------------------------------------------------------------------------
__global__ void init_kernel(unsigned long long* __restrict__ slots,
                            int* __restrict__ gl) {
    int t = threadIdx.x;                 // 1024 threads
#pragma unroll
    for (int i = 0; i < (B_ * G_ * FPS_BLK) / 1024; i++)
        slots[i * 1024 + t] = 0ull;
    if (t < B_) gl[t] = 0;
}

// ---------------------------------------------------------------------------
// Kernel 1: FPS, 4 blocks per batch (one slice of 4096 points each), plus
// fused CNMS in the slice-0 block.
//
// r9 post-mortem: RELEASE/ACQUIRE agent-scope atomics emit L2
// writeback/buffer_inv per op -> ~5500 cyc/step of cache maintenance.
// The exchanged u64 key IS the entire synchronized state (value|~idx,
// fresh address per step, sentinel 0 unreachable: monotone key of any
// non-NaN float has nonzero hi32), pts is read-only, mind/LDS are
// block-local -> NO ordering needed. RELAXED atomics = plain
// cache-bypass LLC access, no fences. All-to-all, busy spin.
// ---------------------------------------------------------------------------
__global__ __launch_bounds__(FPS_T, 4) void fps_cnms_kernel(
    const float4* __restrict__ pts, const int* __restrict__ lengths,
    float* __restrict__ centers_out, int* __restrict__ keep_out,
    unsigned long long* __restrict__ slots) {
    const int b = blockIdx.x & 7;        // batch
    const int slice = blockIdx.x >> 3;   // 0..3
    const int t = threadIdx.x;
    const int lane = t & 63;
    const int wv = t >> 6;
    const int len = lengths[b];
    const float4* p = pts + (size_t)b * N_;
    const int base = slice * SLICE;

    __shared__ float4 s_xy4[SLICE / 2];                   // 32 KB: (xA,yA,xB,yB)
    __shared__ __align__(16) unsigned long long s_part[FPS_W];
    __shared__ int s_bcn[2];
    __shared__ float s_cen[G_][3];                        // centers for CNMS (slice 0)

    // Stage xy pairs -> LDS; z + running min-dist in registers.
    float zs[PPT], mind[PPT];
#pragma unroll
    for (int i2 = 0; i2 < PPT / 2; i2++) {
        int nA = base + (2 * i2) * FPS_T + t;
        int nB = base + (2 * i2 + 1) * FPS_T + t;
        float4 qA = p[nA];
        float4 qB = p[nB];
        s_xy4[i2 * FPS_T + t] = make_float4(qA.x, qA.y, qB.x, qB.y);
        zs[2 * i2]     = qA.z;
        zs[2 * i2 + 1] = qB.z;
        mind[2 * i2]     = (nA < len) ? INFINITY : -INFINITY;
        mind[2 * i2 + 1] = (nB < len) ? INFINITY : -INFINITY;
    }
    __syncthreads();

    int n = 0;   // winner index (uniform across ALL blocks of batch b)
    for (int k = 0; k < G_; k++) {
        float4 c = p[n];   // wave-uniform broadcast load
        float cx = c.x, cy = c.y, cz = c.z;
        if (slice == 0 && t == 0) {
            centers_out[(b * G_ + k) * 3 + 0] = cx;
            centers_out[(b * G_ + k) * 3 + 1] = cy;
            centers_out[(b * G_ + k) * 3 + 2] = cz;
            s_cen[k][0] = cx; s_cen[k][1] = cy; s_cen[k][2] = cz;
        }
        if (k == G_ - 1) break;   // last argmax is discarded by the reference

        // Local update + argmax (ascending n order => strict > keeps smallest n).
        float bv = -INFINITY;
        int bn = 0x7fffffff;
#pragma unroll
        for (int i2 = 0; i2 < PPT / 2; i2++) {
            float4 xy = s_xy4[i2 * FPS_T + t];            // ds_read_b128, 2 points
            float dA = dist2(xy.x, xy.y, zs[2 * i2],     cx, cy, cz);
            float dB = dist2(xy.z, xy.w, zs[2 * i2 + 1], cx, cy, cz);
            float mA = fminf(mind[2 * i2], dA);
            float mB = fminf(mind[2 * i2 + 1], dB);
            mind[2 * i2] = mA;
            mind[2 * i2 + 1] = mB;
            if (mA > bv) { bv = mA; bn = base + (2 * i2) * FPS_T + t; }
            if (mB > bv) { bv = mB; bn = base + (2 * i2 + 1) * FPS_T + t; }
        }
        // Monotone u32 key of bv (any non-NaN float -> nonzero hi word).
        unsigned u = __float_as_uint(bv);
        u = (u & 0x80000000u) ? ~u : (u | 0x80000000u);

        // Wave argmax (VALU pipe): max value, then min index among ties.
        unsigned wmax = wave_umax_bcast(u);
        unsigned ik = (u == wmax) ? (unsigned)bn : 0xffffffffu;
        unsigned wbn = wave_umin_bcast(ik);

        if (lane == 0)
            s_part[wv] = ((unsigned long long)wmax << 32) | (unsigned)(~wbn);
        __syncthreads();

        // Wave 0 reduces the 16 wave partials; t0 does the cross-block merge
        // with RELAXED (fence-free) agent atomics.
        if (wv == 0) {
            unsigned long long kk = s_part[lane & 15];
#pragma unroll
            for (int off = 8; off; off >>= 1)
                kk = umax64(kk, shfl_xor_u64(kk, off));
            if (lane == 0) {
                unsigned long long* slot = slots + ((size_t)b * G_ + k) * FPS_BLK;
                __hip_atomic_store(&slot[slice], kk, __ATOMIC_RELAXED,
                                   __HIP_MEMORY_SCOPE_AGENT);
                unsigned long long best = kk;
#pragma unroll
                for (int j = 0; j < FPS_BLK; j++) {
                    if (j == slice) continue;
                    unsigned long long v;
                    while ((v = __hip_atomic_load(&slot[j], __ATOMIC_RELAXED,
                                                  __HIP_MEMORY_SCOPE_AGENT)) == 0ull)
                        ;
                    best = umax64(best, v);
                }
                s_bcn[k & 1] = (int)(~(unsigned)(best & 0xffffffffull));
            }
        }
        __syncthreads();
        n = s_bcn[k & 1];                                 // broadcast ds_read_b32
    }

    // ---- fused CNMS on wave 0 of the slice-0 block ----
    if (slice == 0 && t < 64) {
        const float THR = (float)((2.0 * 0.1 * (1.0 - 0.7)) * (2.0 * 0.1 * (1.0 - 0.7)));
        float ax = s_cen[t][0],      ay = s_cen[t][1],      az = s_cen[t][2];
        float ex = s_cen[t + 64][0], ey = s_cen[t + 64][1], ez = s_cen[t + 64][2];
        bool k0 = false, k1 = false;
        for (int j = 0; j < G_; j++) {
            float jx = s_cen[j][0], jy = s_cen[j][1], jz = s_cen[j][2];
            bool c0 = k0 && (dist2(ax, ay, az, jx, jy, jz) < THR);
            bool c1 = k1 && (dist2(ex, ey, ez, jx, jy, jz) < THR);
            bool conflict = __any(c0 || c1);
            if (j == t)      k0 = !conflict;
            if (j == t + 64) k1 = !conflict;
        }
        keep_out[b * G_ + t]      = k0 ? 1 : 0;
        keep_out[b * G_ + t + 64] = k1 ? 1 : 0;
    }
}

// ---------------------------------------------------------------------------
// Kernel 2: per-(b,g) ball query (first 128 by index) + top-32 by energy +
// gather/normalize. One 512-thread block per group.
// ---------------------------------------------------------------------------
__global__ __launch_bounds__(BQ_T) void group_kernel(
    const float4* __restrict__ pts, const int* __restrict__ lengths,
    const float* __restrict__ centers, const int* __restrict__ keep,
    float* __restrict__ groups_out, int* __restrict__ gl) {
    const int bid = blockIdx.x;          // b*128 + g
    const int b = bid >> 7;
    const int t = threadIdx.x;
    const int lane = t & 63;
    const int wv = t >> 6;

    const float cx = centers[bid * 3 + 0];
    const float cy = centers[bid * 3 + 1];
    const float cz = centers[bid * 3 + 2];
    float4* out4 = (float4*)(groups_out + (size_t)bid * GS_ * 4);

    if (!keep[bid]) {
        if (t < GS_) {
            float4 o;
            o.x = __fdiv_rn(__fsub_rn(0.f, cx), 0.1f);
            o.y = __fdiv_rn(__fsub_rn(0.f, cy), 0.1f);
            o.z = __fdiv_rn(__fsub_rn(0.f, cz), 0.1f);
            o.w = 0.f;
            out4[t] = o;
        }
        return;
    }

    __shared__ int   s_widx[BQ_W][UK_];
    __shared__ float s_wen[BQ_W][UK_];
    __shared__ int   s_wcnt[BQ_W];
    __shared__ int   s_list[UK_];
    __shared__ float s_en[UK_];
    __shared__ int   s_ord[GS_];

    const int len = lengths[b];
    const float R2 = (float)(0.1 * 0.1);
    const float4* p = pts + (size_t)b * N_;

    // Per-wave ordered stream compaction over its contiguous eighth.
    {
        const int base0 = wv * (N_ / BQ_W);
        int cnt = 0;
        for (int it = 0; it < (N_ / BQ_W) / 64; it++) {
            int n = base0 + it * 64 + lane;
            float4 q = p[n];
            float d2 = dist2(q.x, q.y, q.z, cx, cy, cz);
            bool pred = (n < len) && (d2 <= R2);
            unsigned long long m = __ballot(pred);
            int prefix = __popcll(m & ((1ull << lane) - 1ull));
            int slot = cnt + prefix;
            if (pred && slot < UK_) { s_widx[wv][slot] = n; s_wen[wv][slot] = q.w; }
            cnt += __popcll(m);
        }
        if (lane == 0) s_wcnt[wv] = (cnt < UK_) ? cnt : UK_;
    }
    __syncthreads();

    int M = 0;
#pragma unroll
    for (int w = 0; w < BQ_W; w++) M += s_wcnt[w];
    if (M > UK_) M = UK_;

    // Ordered merge into unified first-M list.
    if (t < UK_ && t < M) {
        int j = t, w = 0;
        while (w < BQ_W - 1 && j >= s_wcnt[w]) { j -= s_wcnt[w]; w++; }
        s_list[t] = s_widx[w][j];
        s_en[t]   = s_wen[w][j];
    }
    __syncthreads();

    // top-32 by energy, tie -> smaller list position (matches lax.top_k)
    if (wv == 0) {
        float v0 = (lane < M) ? s_en[lane] : -INFINITY;
        float v1 = (lane + 64 < M) ? s_en[lane + 64] : -INFINITY;
        for (int k = 0; k < GS_; k++) {
            float bv; int bs;
            if (v0 >= v1) { bv = v0; bs = lane; }
            else          { bv = v1; bs = lane + 64; }
#pragma unroll
            for (int off = 32; off; off >>= 1) {
                float ov = __shfl_xor(bv, off);
                int   os = __shfl_xor(bs, off);
                bool tk = (ov > bv) || (ov == bv && os < bs);
                bv = tk ? ov : bv; bs = tk ? os : bs;
            }
            if (lane == 0) s_ord[k] = (bv == -INFINITY) ? -1 : bs;
            if (bs == lane)           v0 = -INFINITY;
            else if (bs == lane + 64) v1 = -INFINITY;
        }
    }
    __syncthreads();

    if (t < GS_) {
        int o0 = s_ord[0];
        int first = (o0 >= 0) ? s_list[o0] : -1;
        int ok = s_ord[t];
        int ti = (ok >= 0) ? s_list[ok] : -1;
        int f = (ti == -1) ? first : ti;
        float px = 0.f, py = 0.f, pz = 0.f, pw = 0.f;
        if (f >= 0) { float4 q = p[f]; px = q.x; py = q.y; pz = q.z; pw = q.w; }
        float4 o;
        o.x = __fdiv_rn(__fsub_rn(px, cx), 0.1f);
        o.y = __fdiv_rn(__fsub_rn(py, cy), 0.1f);
        o.z = __fdiv_rn(__fsub_rn(pz, cz), 0.1f);
        o.w = __fdiv_rn(pw, 0.1f);
        out4[t] = o;
    }
    if (t == 0 && M >= GS_) atomicAdd(&gl[b], 1);
}

// ---------------------------------------------------------------------------
// Kernel 3: embedding mask
// ---------------------------------------------------------------------------
__global__ void mask_kernel(const int* __restrict__ gl, float* __restrict__ mask_out) {
    int t = threadIdx.x;                 // 1024 threads
    int b = t >> 7, g = t & 127;
    mask_out[t] = (g < gl[b]) ? 1.0f : 0.0f;
}

extern "C" void kernel_launch(void* const* d_in, const int* in_sizes, int n_in,
                              void* d_out, int out_size, void* d_ws, size_t ws_size,
                              hipStream_t stream) {
    const float4* pts = (const float4*)d_in[0];
    const int* lengths = (const int*)d_in[1];
    float* out = (float*)d_out;
    float* groups = out;                               // B*G*GS*4 = 131072
    float* centers = out + (size_t)B_ * G_ * GS_ * 4;  // +3072
    float* mask = centers + (size_t)B_ * G_ * 3;       // +1024
    unsigned long long* slots = (unsigned long long*)d_ws;  // B*G*FPS_BLK u64
    int* keep = (int*)(slots + B_ * G_ * FPS_BLK);     // B*G ints
    int* gl = keep + B_ * G_;                          // B ints

    hipLaunchKernelGGL(init_kernel, dim3(1), dim3(1024), 0, stream, slots, gl);
    hipLaunchKernelGGL(fps_cnms_kernel, dim3(B_ * FPS_BLK), dim3(FPS_T), 0, stream,
                       pts, lengths, centers, keep, slots);
    hipLaunchKernelGGL(group_kernel, dim3(B_ * G_), dim3(BQ_T), 0, stream,
                       pts, lengths, centers, keep, groups, gl);
    hipLaunchKernelGGL(mask_kernel, dim3(1), dim3(B_ * G_), 0, stream, gl, mask);
}

// Round 11
// 298.848 us; speedup vs baseline: 1.3779x; 1.0656x over previous
//
#include <hip/hip_runtime.h>
#include <math.h>

#define B_ 8
#define N_ 16384
#define G_ 128      // NUM_GROUPS
#define GS_ 32      // GROUP_SIZE
#define UK_ 128     // UPSCALE_K
#define FPS_T 1024
#define FPS_W 16    // waves per FPS block
#define FPS_BLK 4   // blocks (CUs) per batch
#define SLICE (N_ / FPS_BLK)     // 4096 points per block
#define PPT (SLICE / FPS_T)      // 4 points per thread
#define BQ_T 512
#define BQ_W 8      // waves per group block

// Exact-rounding distance^2, matching numpy: ((dx*dx + dy*dy) + dz*dz), no FMA.
__device__ __forceinline__ float dist2(float x, float y, float z,
                                       float cx, float cy, float cz) {
    float dx = __fsub_rn(x, cx);
    float dy = __fsub_rn(y, cy);
    float dz = __fsub_rn(z, cz);
    return __fadd_rn(__fadd_rn(__fmul_rn(dx, dx), __fmul_rn(dy, dy)),
                     __fmul_rn(dz, dz));
}

__device__ __forceinline__ unsigned long long shfl_xor_u64(unsigned long long v, int m) {
    int lo = __shfl_xor((int)(unsigned)(v & 0xffffffffull), m);
    int hi = __shfl_xor((int)(unsigned)(v >> 32), m);
    return ((unsigned long long)(unsigned)hi << 32) | (unsigned)lo;
}

__device__ __forceinline__ unsigned long long umax64(unsigned long long a,
                                                     unsigned long long b) {
    return a > b ? a : b;
}

// Wave64 max-reduce on the VALU pipe via DPP (no DS traffic).
__device__ __forceinline__ unsigned wave_umax_bcast(unsigned v) {
    unsigned t;
    t = (unsigned)__builtin_amdgcn_update_dpp(0, (int)v, 0x111, 0xf, 0xf, false); v = v > t ? v : t;
    t = (unsigned)__builtin_amdgcn_update_dpp(0, (int)v, 0x112, 0xf, 0xf, false); v = v > t ? v : t;
    t = (unsigned)__builtin_amdgcn_update_dpp(0, (int)v, 0x114, 0xf, 0xf, false); v = v > t ? v : t;
    t = (unsigned)__builtin_amdgcn_update_dpp(0, (int)v, 0x118, 0xf, 0xf, false); v = v > t ? v : t;
    t = (unsigned)__builtin_amdgcn_update_dpp(0, (int)v, 0x142, 0xa, 0xf, false); v = v > t ? v : t;
    t = (unsigned)__builtin_amdgcn_update_dpp(0, (int)v, 0x143, 0xc, 0xf, false); v = v > t ? v : t;
    return (unsigned)__builtin_amdgcn_readlane((int)v, 63);
}
__device__ __forceinline__ unsigned wave_umin_bcast(unsigned v) {
    unsigned t;
    t = (unsigned)__builtin_amdgcn_update_dpp(-1, (int)v, 0x111, 0xf, 0xf, false); v = v < t ? v : t;
    t = (unsigned)__builtin_amdgcn_update_dpp(-1, (int)v, 0x112, 0xf, 0xf, false); v = v < t ? v : t;
    t = (unsigned)__builtin_amdgcn_update_dpp(-1, (int)v, 0x114, 0xf, 0xf, false); v = v < t ? v : t;
    t = (unsigned)__builtin_amdgcn_update_dpp(-1, (int)v, 0x118, 0xf, 0xf, false); v = v < t ? v : t;
    t = (unsigned)__builtin_amdgcn_update_dpp(-1, (int)v, 0x142, 0xa, 0xf, false); v = v < t ? v : t;
    t = (unsigned)__builtin_amdgcn_update_dpp(-1, (int)v, 0x143, 0xc, 0xf, false); v = v < t ? v : t;
    return (unsigned)__builtin_amdgcn_readlane((int)v, 63);
}

// ---------------------------------------------------------------------------
// Kernel 0: zero the cross-block slots + gl (ws is poisoned 0xAA; must be
// stream-ordered BEFORE fps so no block can see poison as a valid key).
// ---------------------------------------------------------------------------
__global__ void init_kernel(unsigned long long* __restrict__ slots,
                            int* __restrict__ gl) {
    int t = threadIdx.x;                 // 1024 threads
#pragma unroll
    for (int i = 0; i < (B_ * G_ * FPS_BLK) / 1024; i++)
        slots[i * 1024 + t] = 0ull;
    if (t < B_) gl[t] = 0;
}

// ---------------------------------------------------------------------------
// Kernel 1: FPS, 4 blocks per batch (one slice of 4096 points each), plus
// fused CNMS in the slice-0 block.
//
// r10 post-mortem: relaxed atomics removed the fences (337->230us) but
// lane0 polled the 3 remote slots SEQUENTIALLY => up to 3 serial LLC RTTs
// (~2500 cyc) per step. This round: lanes 0..3 of wave 0 each own one
// slot; lane==slice keeps its local key (no self round-trip), the other
// 3 lanes spin on their slot with ONE vector load instruction per
// iteration (32B contiguous => single transaction). Merge = 2-level
// shfl_xor over lanes 0..3. Bit-identical reduction & tie-break.
// ---------------------------------------------------------------------------
__global__ __launch_bounds__(FPS_T, 4) void fps_cnms_kernel(
    const float4* __restrict__ pts, const int* __restrict__ lengths,
    float* __restrict__ centers_out, int* __restrict__ keep_out,
    unsigned long long* __restrict__ slots) {
    const int b = blockIdx.x & 7;        // batch
    const int slice = blockIdx.x >> 3;   // 0..3
    const int t = threadIdx.x;
    const int lane = t & 63;
    const int wv = t >> 6;
    const int len = lengths[b];
    const float4* p = pts + (size_t)b * N_;
    const int base = slice * SLICE;

    __shared__ float4 s_xy4[SLICE / 2];                   // 32 KB: (xA,yA,xB,yB)
    __shared__ __align__(16) unsigned long long s_part[FPS_W];
    __shared__ int s_bcn[2];
    __shared__ float s_cen[G_][3];                        // centers for CNMS (slice 0)

    // Stage xy pairs -> LDS; z + running min-dist in registers.
    float zs[PPT], mind[PPT];
#pragma unroll
    for (int i2 = 0; i2 < PPT / 2; i2++) {
        int nA = base + (2 * i2) * FPS_T + t;
        int nB = base + (2 * i2 + 1) * FPS_T + t;
        float4 qA = p[nA];
        float4 qB = p[nB];
        s_xy4[i2 * FPS_T + t] = make_float4(qA.x, qA.y, qB.x, qB.y);
        zs[2 * i2]     = qA.z;
        zs[2 * i2 + 1] = qB.z;
        mind[2 * i2]     = (nA < len) ? INFINITY : -INFINITY;
        mind[2 * i2 + 1] = (nB < len) ? INFINITY : -INFINITY;
    }
    __syncthreads();

    int n = 0;   // winner index (uniform across ALL blocks of batch b)
    for (int k = 0; k < G_; k++) {
        float4 c = p[n];   // wave-uniform broadcast load
        float cx = c.x, cy = c.y, cz = c.z;
        if (slice == 0 && t == 0) {
            centers_out[(b * G_ + k) * 3 + 0] = cx;
            centers_out[(b * G_ + k) * 3 + 1] = cy;
            centers_out[(b * G_ + k) * 3 + 2] = cz;
            s_cen[k][0] = cx; s_cen[k][1] = cy; s_cen[k][2] = cz;
        }
        if (k == G_ - 1) break;   // last argmax is discarded by the reference

        // Local update + argmax (ascending n order => strict > keeps smallest n).
        float bv = -INFINITY;
        int bn = 0x7fffffff;
#pragma unroll
        for (int i2 = 0; i2 < PPT / 2; i2++) {
            float4 xy = s_xy4[i2 * FPS_T + t];            // ds_read_b128, 2 points
            float dA = dist2(xy.x, xy.y, zs[2 * i2],     cx, cy, cz);
            float dB = dist2(xy.z, xy.w, zs[2 * i2 + 1], cx, cy, cz);
            float mA = fminf(mind[2 * i2], dA);
            float mB = fminf(mind[2 * i2 + 1], dB);
            mind[2 * i2] = mA;
            mind[2 * i2 + 1] = mB;
            if (mA > bv) { bv = mA; bn = base + (2 * i2) * FPS_T + t; }
            if (mB > bv) { bv = mB; bn = base + (2 * i2 + 1) * FPS_T + t; }
        }
        // Monotone u32 key of bv (any non-NaN float -> nonzero hi word).
        unsigned u = __float_as_uint(bv);
        u = (u & 0x80000000u) ? ~u : (u | 0x80000000u);

        // Wave argmax (VALU pipe): max value, then min index among ties.
        unsigned wmax = wave_umax_bcast(u);
        unsigned ik = (u == wmax) ? (unsigned)bn : 0xffffffffu;
        unsigned wbn = wave_umin_bcast(ik);

        if (lane == 0)
            s_part[wv] = ((unsigned long long)wmax << 32) | (unsigned)(~wbn);
        __syncthreads();

        // Wave 0: 16 partials -> block key (all lanes); then cross-block merge
        // with per-lane parallel polling (lanes 0..3, one slot each).
        if (wv == 0) {
            unsigned long long kk = s_part[lane & 15];
#pragma unroll
            for (int off = 8; off; off >>= 1)
                kk = umax64(kk, shfl_xor_u64(kk, off));

            unsigned long long* slot = slots + ((size_t)b * G_ + k) * FPS_BLK;
            if (lane == 0)
                __hip_atomic_store(&slot[slice], kk, __ATOMIC_RELAXED,
                                   __HIP_MEMORY_SCOPE_AGENT);
            unsigned long long v = kk;     // own block's key for lane==slice
            if (lane < FPS_BLK && lane != slice) {
                do {
                    v = __hip_atomic_load(&slot[lane], __ATOMIC_RELAXED,
                                          __HIP_MEMORY_SCOPE_AGENT);
                } while (v == 0ull);
            }
            // Merge lanes 0..3 (lanes >=4 hold kk; irrelevant to lane0 result).
            unsigned long long m = umax64(v, shfl_xor_u64(v, 1));
            m = umax64(m, shfl_xor_u64(m, 2));
            if (lane == 0)
                s_bcn[k & 1] = (int)(~(unsigned)(m & 0xffffffffull));
        }
        __syncthreads();
        n = s_bcn[k & 1];                                 // broadcast ds_read_b32
    }

    // ---- fused CNMS on wave 0 of the slice-0 block ----
    if (slice == 0 && t < 64) {
        const float THR = (float)((2.0 * 0.1 * (1.0 - 0.7)) * (2.0 * 0.1 * (1.0 - 0.7)));
        float ax = s_cen[t][0],      ay = s_cen[t][1],      az = s_cen[t][2];
        float ex = s_cen[t + 64][0], ey = s_cen[t + 64][1], ez = s_cen[t + 64][2];
        bool k0 = false, k1 = false;
        for (int j = 0; j < G_; j++) {
            float jx = s_cen[j][0], jy = s_cen[j][1], jz = s_cen[j][2];
            bool c0 = k0 && (dist2(ax, ay, az, jx, jy, jz) < THR);
            bool c1 = k1 && (dist2(ex, ey, ez, jx, jy, jz) < THR);
            bool conflict = __any(c0 || c1);
            if (j == t)      k0 = !conflict;
            if (j == t + 64) k1 = !conflict;
        }
        keep_out[b * G_ + t]      = k0 ? 1 : 0;
        keep_out[b * G_ + t + 64] = k1 ? 1 : 0;
    }
}

// ---------------------------------------------------------------------------
// Kernel 2: per-(b,g) ball query (first 128 by index) + top-32 by energy +
// gather/normalize. One 512-thread block per group.
// ---------------------------------------------------------------------------
__global__ __launch_bounds__(BQ_T) void group_kernel(
    const float4* __restrict__ pts, const int* __restrict__ lengths,
    const float* __restrict__ centers, const int* __restrict__ keep,
    float* __restrict__ groups_out, int* __restrict__ gl) {
    const int bid = blockIdx.x;          // b*128 + g
    const int b = bid >> 7;
    const int t = threadIdx.x;
    const int lane = t & 63;
    const int wv = t >> 6;

    const float cx = centers[bid * 3 + 0];
    const float cy = centers[bid * 3 + 1];
    const float cz = centers[bid * 3 + 2];
    float4* out4 = (float4*)(groups_out + (size_t)bid * GS_ * 4);

    if (!keep[bid]) {
        if (t < GS_) {
            float4 o;
            o.x = __fdiv_rn(__fsub_rn(0.f, cx), 0.1f);
            o.y = __fdiv_rn(__fsub_rn(0.f, cy), 0.1f);
            o.z = __fdiv_rn(__fsub_rn(0.f, cz), 0.1f);
            o.w = 0.f;
            out4[t] = o;
        }
        return;
    }

    __shared__ int   s_widx[BQ_W][UK_];
    __shared__ float s_wen[BQ_W][UK_];
    __shared__ int   s_wcnt[BQ_W];
    __shared__ int   s_list[UK_];
    __shared__ float s_en[UK_];
    __shared__ int   s_ord[GS_];

    const int len = lengths[b];
    const float R2 = (float)(0.1 * 0.1);
    const float4* p = pts + (size_t)b * N_;

    // Per-wave ordered stream compaction over its contiguous eighth.
    {
        const int base0 = wv * (N_ / BQ_W);
        int cnt = 0;
        for (int it = 0; it < (N_ / BQ_W) / 64; it++) {
            int n = base0 + it * 64 + lane;
            float4 q = p[n];
            float d2 = dist2(q.x, q.y, q.z, cx, cy, cz);
            bool pred = (n < len) && (d2 <= R2);
            unsigned long long m = __ballot(pred);
            int prefix = __popcll(m & ((1ull << lane) - 1ull));
            int slot = cnt + prefix;
            if (pred && slot < UK_) { s_widx[wv][slot] = n; s_wen[wv][slot] = q.w; }
            cnt += __popcll(m);
        }
        if (lane == 0) s_wcnt[wv] = (cnt < UK_) ? cnt : UK_;
    }
    __syncthreads();

    int M = 0;
#pragma unroll
    for (int w = 0; w < BQ_W; w++) M += s_wcnt[w];
    if (M > UK_) M = UK_;

    // Ordered merge into unified first-M list.
    if (t < UK_ && t < M) {
        int j = t, w = 0;
        while (w < BQ_W - 1 && j >= s_wcnt[w]) { j -= s_wcnt[w]; w++; }
        s_list[t] = s_widx[w][j];
        s_en[t]   = s_wen[w][j];
    }
    __syncthreads();

    // top-32 by energy, tie -> smaller list position (matches lax.top_k)
    if (wv == 0) {
        float v0 = (lane < M) ? s_en[lane] : -INFINITY;
        float v1 = (lane + 64 < M) ? s_en[lane + 64] : -INFINITY;
        for (int k = 0; k < GS_; k++) {
            float bv; int bs;
            if (v0 >= v1) { bv = v0; bs = lane; }
            else          { bv = v1; bs = lane + 64; }
#pragma unroll
            for (int off = 32; off; off >>= 1) {
                float ov = __shfl_xor(bv, off);
                int   os = __shfl_xor(bs, off);
                bool tk = (ov > bv) || (ov == bv && os < bs);
                bv = tk ? ov : bv; bs = tk ? os : bs;
            }
            if (lane == 0) s_ord[k] = (bv == -INFINITY) ? -1 : bs;
            if (bs == lane)           v0 = -INFINITY;
            else if (bs == lane + 64) v1 = -INFINITY;
        }
    }
    __syncthreads();

    if (t < GS_) {
        int o0 = s_ord[0];
        int first = (o0 >= 0) ? s_list[o0] : -1;
        int ok = s_ord[t];
        int ti = (ok >= 0) ? s_list[ok] : -1;
        int f = (ti == -1) ? first : ti;
        float px = 0.f, py = 0.f, pz = 0.f, pw = 0.f;
        if (f >= 0) { float4 q = p[f]; px = q.x; py = q.y; pz = q.z; pw = q.w; }
        float4 o;
        o.x = __fdiv_rn(__fsub_rn(px, cx), 0.1f);
        o.y = __fdiv_rn(__fsub_rn(py, cy), 0.1f);
        o.z = __fdiv_rn(__fsub_rn(pz, cz), 0.1f);
        o.w = __fdiv_rn(pw, 0.1f);
        out4[t] = o;
    }
    if (t == 0 && M >= GS_) atomicAdd(&gl[b], 1);
}

// ---------------------------------------------------------------------------
// Kernel 3: embedding mask
// ---------------------------------------------------------------------------
__global__ void mask_kernel(const int* __restrict__ gl, float* __restrict__ mask_out) {
    int t = threadIdx.x;                 // 1024 threads
    int b = t >> 7, g = t & 127;
    mask_out[t] = (g < gl[b]) ? 1.0f : 0.0f;
}

extern "C" void kernel_launch(void* const* d_in, const int* in_sizes, int n_in,
                              void* d_out, int out_size, void* d_ws, size_t ws_size,
                              hipStream_t stream) {
    const float4* pts = (const float4*)d_in[0];
    const int* lengths = (const int*)d_in[1];
    float* out = (float*)d_out;
    float* groups = out;                               // B*G*GS*4 = 131072
    float* centers = out + (size_t)B_ * G_ * GS_ * 4;  // +3072
    float* mask = centers + (size_t)B_ * G_ * 3;       // +1024
    unsigned long long* slots = (unsigned long long*)d_ws;  // B*G*FPS_BLK u64
    int* keep = (int*)(slots + B_ * G_ * FPS_BLK);     // B*G ints
    int* gl = keep + B_ * G_;                          // B ints

    hipLaunchKernelGGL(init_kernel, dim3(1), dim3(1024), 0, stream, slots, gl);
    hipLaunchKernelGGL(fps_cnms_kernel, dim3(B_ * FPS_BLK), dim3(FPS_T), 0, stream,
                       pts, lengths, centers, keep, slots);
    hipLaunchKernelGGL(group_kernel, dim3(B_ * G_), dim3(BQ_T), 0, stream,
                       pts, lengths, centers, keep, groups, gl);
    hipLaunchKernelGGL(mask_kernel, dim3(1), dim3(B_ * G_), 0, stream, gl, mask);
}